// Round 2
// baseline (301.763 us; speedup 1.0000x reference)
//
#include <hip/hip_runtime.h>
#include <hip/hip_bf16.h>

// Problem constants: B=1, N=128, L=256, D=256, P=128, H=8, DH=32
// Established: fp32 inputs, fp32 output; bf16-rounded ref, threshold 0.0289.
#define NN 128
#define LL 256
#define DD 256
#define PP 128
#define HH 8
#define DHH 32

typedef __bf16 bf16x8 __attribute__((ext_vector_type(8)));
typedef short s16x4 __attribute__((ext_vector_type(4)));
typedef float f32x4 __attribute__((ext_vector_type(4)));
typedef unsigned int u32x2 __attribute__((ext_vector_type(2)));

// async global->LDS, 16B per lane (dest = wave-uniform base + lane*16)
__device__ __forceinline__ void gload_lds16(const void* g, void* l) {
  __builtin_amdgcn_global_load_lds(
      (const __attribute__((address_space(1))) void*)g,
      (__attribute__((address_space(3))) void*)l, 16, 0, 0);
}

// ---------------------------------------------------------------------------
// fp32 -> bf16 bulk convert
// ---------------------------------------------------------------------------
__global__ __launch_bounds__(256) void cvt_bf16(
    const float* __restrict__ src, __hip_bfloat16* __restrict__ dst, int n) {
  for (int i = (blockIdx.x * 256 + threadIdx.x) * 4; i < n; i += gridDim.x * 1024) {
    float4 v = *(const float4*)(src + i);
    ushort4 o;
    o.x = __bfloat16_as_ushort(__float2bfloat16(v.x));
    o.y = __bfloat16_as_ushort(__float2bfloat16(v.y));
    o.z = __bfloat16_as_ushort(__float2bfloat16(v.z));
    o.w = __bfloat16_as_ushort(__float2bfloat16(v.w));
    *(ushort4*)(dst + i) = o;
  }
}

// ---------------------------------------------------------------------------
// transpose + convert: src [K][N] fp32 -> dst [N][K] bf16
// ---------------------------------------------------------------------------
__global__ __launch_bounds__(256) void transpose_cvt(
    const float* __restrict__ src, __hip_bfloat16* __restrict__ dst,
    int K, int N) {
  __shared__ float t[32][33];
  int n0 = blockIdx.x * 32, k0 = blockIdx.y * 32;
  int tx = threadIdx.x & 31, ty = threadIdx.x >> 5;
  for (int i = 0; i < 4; ++i) {
    int ky = ty + i * 8;
    t[ky][tx] = src[(size_t)(k0 + ky) * N + n0 + tx];
  }
  __syncthreads();
  for (int i = 0; i < 4; ++i) {
    int ny = ty + i * 8;
    dst[(size_t)(n0 + ny) * K + k0 + tx] = __float2bfloat16(t[tx][ny]);
  }
}

// ---------------------------------------------------------------------------
// mask normalization (int32 / int8 / bf16 / fp32 -> float 1.0/0.0), parallel
// ---------------------------------------------------------------------------
#define MODE_I32 0
#define MODE_I8 1
#define MODE_BF16 2
#define MODE_F32 3

__global__ __launch_bounds__(256) void mask_expand(
    const unsigned char* __restrict__ mraw, float* __restrict__ mout) {
  __shared__ int s_or1, s_or2, s_or3, s_max, s_mode;
  int tid = threadIdx.x;
  if (tid == 0) { s_or1 = 0; s_or2 = 0; s_or3 = 0; s_max = 0; }
  __syncthreads();
  int or1 = 0, or2 = 0, or3 = 0, mx = 0;
  for (int j = tid; j < 4096; j += 256) {
    int b = mraw[j];
    mx = mx > b ? mx : b;
    int r = j & 3;
    if (r == 1) or1 |= b;
    else if (r == 2) or2 |= b;
    else if (r == 3) or3 |= b;
  }
  atomicOr(&s_or1, or1); atomicOr(&s_or2, or2); atomicOr(&s_or3, or3);
  atomicMax(&s_max, mx);
  __syncthreads();
  if (tid == 0) {
    int mode;
    if (s_max <= 1) mode = ((s_or1 | s_or2 | s_or3) == 0) ? MODE_I32 : MODE_I8;
    else            mode = (s_or1 != 0) ? MODE_BF16 : MODE_F32;
    s_mode = mode;
  }
  __syncthreads();
  int mode = s_mode;
  int i0 = blockIdx.x * 1024;
  for (int i = i0 + tid; i < i0 + 1024; i += 256) {
    int v;
    if (mode == MODE_I32)       v = ((const int*)mraw)[i] != 0;
    else if (mode == MODE_I8)   v = mraw[i] != 0;
    else if (mode == MODE_BF16) v = ((const unsigned short*)mraw)[i] != 0;
    else                        v = ((const unsigned int*)mraw)[i] != 0;
    mout[i] = v ? 1.f : 0.f;
  }
}

// ---------------------------------------------------------------------------
// MFMA GEMM main loop (A [M][256] bf16, Bt [N][256] bf16 = B^T).
// 128x128 tile, BK=32, 4 waves of 64x64, 4x4 mfma_f32_16x16x32_bf16.
// Staging now via global_load_lds width=16 (m97 structure): no VGPR
// round-trip, loads stay in flight until the pre-compute barrier.
// ---------------------------------------------------------------------------
#define GEMM_MAINLOOP(Aptr, Btptr)                                            \
  __shared__ __align__(16) __hip_bfloat16 Asm[128 * 32];                      \
  __shared__ __align__(16) __hip_bfloat16 Bsm[128 * 32];                      \
  int tid = threadIdx.x;                                                      \
  int lane = tid & 63;                                                        \
  int wv = tid >> 6;                                                          \
  int wm = (wv >> 1) * 64, wn = (wv & 1) * 64;                                \
  int lr = lane & 15, quad = lane >> 4;                                       \
  int bm = blockIdx.x, bn = blockIdx.y;                                       \
  f32x4 acc[4][4];                                                            \
  for (int i = 0; i < 4; ++i)                                                 \
    for (int j = 0; j < 4; ++j) acc[i][j] = (f32x4){0.f, 0.f, 0.f, 0.f};      \
  for (int ks = 0; ks < 8; ++ks) {                                            \
    int k0 = ks * 32;                                                         \
    if (ks) __syncthreads();                                                  \
    for (int i = 0; i < 2; ++i) {                                             \
      int c = tid + i * 256;                                                  \
      int row = c >> 2, cc = c & 3;                                           \
      int ldsbase = (wv * 64 + i * 256) * 8; /* elements; wave-uniform */     \
      gload_lds16(Aptr + ((size_t)(bm * 128 + row)) * 256 + k0 + cc * 8,      \
                  Asm + ldsbase);                                             \
      gload_lds16(Btptr + ((size_t)(bn * 128 + row)) * 256 + k0 + cc * 8,     \
                  Bsm + ldsbase);                                             \
    }                                                                         \
    __syncthreads();                                                          \
    bf16x8 af[4], bfr[4];                                                     \
    for (int mi = 0; mi < 4; ++mi)                                            \
      af[mi] = *(const bf16x8*)&Asm[(wm + mi * 16 + lr) * 32 + quad * 8];     \
    for (int ni = 0; ni < 4; ++ni)                                            \
      bfr[ni] = *(const bf16x8*)&Bsm[(wn + ni * 16 + lr) * 32 + quad * 8];    \
    for (int mi = 0; mi < 4; ++mi)                                            \
      for (int ni = 0; ni < 4; ++ni)                                          \
        acc[mi][ni] = __builtin_amdgcn_mfma_f32_16x16x32_bf16(                \
            af[mi], bfr[ni], acc[mi][ni], 0, 0, 0);                           \
  }

// QKV: q,k -> [n][h][l][dh]; v -> [n][h][dh][l] (transposed for attention).
__global__ __launch_bounds__(256) void qkv_gemm_mfma(
    const __hip_bfloat16* __restrict__ A,
    const __hip_bfloat16* __restrict__ Bt,
    __hip_bfloat16* __restrict__ qb,
    __hip_bfloat16* __restrict__ kb,
    __hip_bfloat16* __restrict__ vb) {
  GEMM_MAINLOOP(A, Bt)
  for (int mi = 0; mi < 4; ++mi) {
    for (int ni = 0; ni < 4; ++ni) {
      int gcol = bn * 128 + wn + ni * 16 + lr;
      int t = gcol >> 8, rem = gcol & 255;
      int h = rem >> 5, dh = rem & 31;
      for (int r = 0; r < 4; ++r) {
        int grow = bm * 128 + wm + mi * 16 + quad * 4 + r;
        int n = grow >> 8, l = grow & 255;
        __hip_bfloat16 val = __float2bfloat16(acc[mi][ni][r]);
        if (t == 0)
          qb[(size_t)(((n * HH + h) * LL + l)) * DHH + dh] = val;
        else if (t == 1)
          kb[(size_t)(((n * HH + h) * LL + l)) * DHH + dh] = val;
        else
          vb[(size_t)(((n * HH + h) * DHH + dh)) * LL + l] = val;
      }
    }
  }
}

__global__ __launch_bounds__(256) void out_gemm_mfma(
    const __hip_bfloat16* __restrict__ A,
    const __hip_bfloat16* __restrict__ Bt,
    const float* __restrict__ bout,
    float* __restrict__ C) {
  GEMM_MAINLOOP(A, Bt)
  for (int mi = 0; mi < 4; ++mi) {
    for (int ni = 0; ni < 4; ++ni) {
      int gcol = bn * 128 + wn + ni * 16 + lr;
      float bo = bout[gcol];
      for (int r = 0; r < 4; ++r) {
        int grow = bm * 128 + wm + mi * 16 + quad * 4 + r;
        C[(size_t)grow * 256 + gcol] = acc[mi][ni][r] + bo;
      }
    }
  }
}

// ---------------------------------------------------------------------------
// pair bias -> expb[h][q][k] = exp(pair@w_pb + b_pb - 12) as bf16.
// (fixed softmax shift; softmax is shift-invariant, scores bounded |s|<~10.
//  bf16 on the exp VALUE is a ~0.2% multiplicative error on softmax weights,
//  well inside the 0.0289 threshold.)
// ---------------------------------------------------------------------------
__global__ __launch_bounds__(256) void pair_bias_kernel(
    const float* __restrict__ pair,
    const float* __restrict__ w_pb,
    const float* __restrict__ b_pb,
    __hip_bfloat16* __restrict__ expb) {
  __shared__ float wp[128][9];
  __shared__ float rows[32][129];
  int tid = threadIdx.x;
  for (int i = 0; i < 4; ++i) {
    int e = tid + i * 256;
    wp[e >> 3][e & 7] = w_pb[e];
  }
  int row0 = blockIdx.x * 32;
  const float* src = pair + (size_t)row0 * PP;
  for (int i = 0; i < 16; ++i) {
    int e = tid + i * 256;
    int r = e >> 7, c = e & 127;
    rows[r][c] = src[r * 128 + c];
  }
  __syncthreads();
  int h = tid >> 5, rl = tid & 31;
  float acc = b_pb[h] - 12.0f;
  for (int p = 0; p < 128; ++p)
    acc += rows[rl][p] * wp[p][h];
  int row = row0 + rl;
  int i = row >> 8, j = row & 255;
  expb[((size_t)(h * LL + i)) * LL + j] = __float2bfloat16(__expf(acc));
}

// ---------------------------------------------------------------------------
// Flash-style MFMA attention, fixed-shift softmax, zero LDS, SWAPPED QK^T
// (S^T = mfma(K,Q); P^T packs directly into the 16x16x16 PV B-fragment).
//
// Round-2 restructure: the kernel was memory-LATENCY-bound (35% issue, 11%
// HBM, ~134 serialized load round-trips/wave at VGPR=108). Fix: explicit
// register double-buffering — all of kt+1's K/V/mask fragments issue before
// kt's compute, expb one mi-step ahead — with __launch_bounds__(256,2)
// giving the compiler ~256 VGPR to keep them in flight. Bias stream is
// pre-exponentiated bf16 (half the bytes, no fma in the exp chain).
// ---------------------------------------------------------------------------
__global__ __launch_bounds__(256, 2) void attn_mfma(
    const __hip_bfloat16* __restrict__ qb,
    const __hip_bfloat16* __restrict__ kb,
    const __hip_bfloat16* __restrict__ vbt,
    const __hip_bfloat16* __restrict__ expb,  // [h][q][k] = exp(bias-12) bf16
    const float* __restrict__ maskf,          // [n][k] 1.0/0.0
    __hip_bfloat16* __restrict__ ao) {
  int bx = blockIdx.x;
  int h = bx >> 7, n = bx & 127;
  int nh = n * HH + h;
  int tid = threadIdx.x, lane = tid & 63, wv = tid >> 6;
  int lr = lane & 15, quad = lane >> 4;
  int wm = wv * 64;
  size_t base = (size_t)nh * (LL * DHH);

  const __hip_bfloat16* qp = qb + base;
  const __hip_bfloat16* kp = kb + base;
  const __hip_bfloat16* vp = vbt + base;
  const __hip_bfloat16* ep = expb + (size_t)h * LL * LL;
  const float* mrow = maskf + n * LL;

  const float cs = 0.17677669529663687f * 1.4426950408889634f;  // scale*log2e

  // Q fragments (row q = wm+mi*16+lr, dh = quad*8..+7); B-operand of QK^T.
  bf16x8 aq[4];
#pragma unroll
  for (int mi = 0; mi < 4; ++mi)
    aq[mi] = *(const bf16x8*)(qp + (size_t)(wm + mi * 16 + lr) * DHH + quad * 8);

  // double-buffered kt-level operands
  bf16x8 bk[2][4];      // K frags (A-operand)
  s16x4 av[2][4][2];    // V^T frags (A-operand of PV)
  f32x4 mw[2][4];       // mask multipliers
  uint2 eb[2][4];       // expb bf16x4, one mi at a time

#define LOADKT(B, KT)                                                         \
  do {                                                                        \
    int j0_ = (KT) * 64;                                                      \
    _Pragma("unroll") for (int nj = 0; nj < 4; ++nj)                          \
        bk[B][nj] =                                                           \
        *(const bf16x8*)(kp + (size_t)(j0_ + nj * 16 + lr) * DHH + quad * 8); \
    _Pragma("unroll") for (int nj = 0; nj < 4; ++nj)                          \
        _Pragma("unroll") for (int no = 0; no < 2; ++no)                      \
        av[B][nj][no] = *(const s16x4*)(vp + (size_t)(no * 16 + lr) * LL +    \
                                        j0_ + nj * 16 + quad * 4);            \
    _Pragma("unroll") for (int nj = 0; nj < 4; ++nj)                          \
        mw[B][nj] = *(const f32x4*)(mrow + j0_ + nj * 16 + quad * 4);         \
  } while (0)

#define LOADEB(B, KT, MI)                                                     \
  do {                                                                        \
    const __hip_bfloat16* er_ =                                               \
        ep + (size_t)(wm + (MI) * 16 + lr) * LL + (KT) * 64;                  \
    _Pragma("unroll") for (int nj = 0; nj < 4; ++nj)                          \
        eb[B][nj] = *(const uint2*)(er_ + nj * 16 + quad * 4);                \
  } while (0)

  LOADKT(0, 0);
  LOADEB(0, 0, 0);

  float lsum[4] = {0.f, 0.f, 0.f, 0.f};
  f32x4 o_acc[4][2];
#pragma unroll
  for (int mi = 0; mi < 4; ++mi)
#pragma unroll
    for (int no = 0; no < 2; ++no) o_acc[mi][no] = (f32x4){0.f, 0.f, 0.f, 0.f};

#pragma unroll
  for (int kt = 0; kt < 4; ++kt) {
    const int cur = kt & 1, nxt = cur ^ 1;
    if (kt < 3) LOADKT(nxt, kt + 1);  // full kt ahead: HBM latency hidden

#pragma unroll
    for (int mi = 0; mi < 4; ++mi) {
      const int ec = mi & 1, en = ec ^ 1;
      if (mi < 3) LOADEB(en, kt, mi + 1);       // one mi-phase ahead (L2)
      else if (kt < 3) LOADEB(en, kt + 1, 0);

      // S^T tiles: row k = j0+nj*16+quad*4+r, col q = wm+mi*16+lr
      f32x4 s[4];
#pragma unroll
      for (int nj = 0; nj < 4; ++nj)
        s[nj] = __builtin_amdgcn_mfma_f32_16x16x32_bf16(
            bk[cur][nj], aq[mi], (f32x4){0.f, 0.f, 0.f, 0.f}, 0, 0, 0);

#pragma unroll
      for (int nj = 0; nj < 4; ++nj) {
        uint2 e = eb[ec][nj];
        f32x4 m4 = mw[cur][nj];
        float em0 = __uint_as_float(e.x << 16) * m4[0];
        float em1 = __uint_as_float(e.x & 0xffff0000u) * m4[1];
        float em2 = __uint_as_float(e.y << 16) * m4[2];
        float em3 = __uint_as_float(e.y & 0xffff0000u) * m4[3];
        float p0 = exp2f(s[nj][0] * cs) * em0;
        float p1 = exp2f(s[nj][1] * cs) * em1;
        float p2 = exp2f(s[nj][2] * cs) * em2;
        float p3 = exp2f(s[nj][3] * cs) * em3;
        lsum[mi] += (p0 + p1) + (p2 + p3);
        // pack P^T B-fragment: elem j <-> k = quad*4 + j (r order preserved)
        unsigned lo = ((unsigned)__bfloat16_as_ushort(__float2bfloat16(p1)) << 16) |
                      (unsigned)__bfloat16_as_ushort(__float2bfloat16(p0));
        unsigned hi = ((unsigned)__bfloat16_as_ushort(__float2bfloat16(p3)) << 16) |
                      (unsigned)__bfloat16_as_ushort(__float2bfloat16(p2));
        u32x2 pu = {lo, hi};
        s16x4 pb = __builtin_bit_cast(s16x4, pu);
#pragma unroll
        for (int no = 0; no < 2; ++no)
          o_acc[mi][no] = __builtin_amdgcn_mfma_f32_16x16x16bf16_1k(
              av[cur][nj][no], pb, o_acc[mi][no], 0, 0, 0);
      }
    }
  }

  // epilogue: O^T tile (row dh = no*16+quad*4+r, col q = wm+mi*16+lr).
#pragma unroll
  for (int mi = 0; mi < 4; ++mi) {
    float ls = lsum[mi];
    ls += __shfl_xor(ls, 16);
    ls += __shfl_xor(ls, 32);
    float inv = (ls > 0.f) ? 1.f / ls : 0.f;
    int q = wm + mi * 16 + lr;
#pragma unroll
    for (int no = 0; no < 2; ++no) {
      f32x4 o = o_acc[mi][no];
      ushort4 w;
      w.x = __bfloat16_as_ushort(__float2bfloat16(o[0] * inv));
      w.y = __bfloat16_as_ushort(__float2bfloat16(o[1] * inv));
      w.z = __bfloat16_as_ushort(__float2bfloat16(o[2] * inv));
      w.w = __bfloat16_as_ushort(__float2bfloat16(o[3] * inv));
      *(ushort4*)(ao + (size_t)n * (LL * DD) + (size_t)q * DD +
                  h * DHH + no * 16 + quad * 4) = w;
    }
  }
#undef LOADKT
#undef LOADEB
}

extern "C" void kernel_launch(void* const* d_in, const int* in_sizes, int n_in,
                              void* d_out, int out_size, void* d_ws, size_t ws_size,
                              hipStream_t stream) {
  const float* msa   = (const float*)d_in[0];
  const float* pair  = (const float*)d_in[1];
  const unsigned char* mask = (const unsigned char*)d_in[2];
  const float* w_qkv = (const float*)d_in[3];
  const float* w_pb  = (const float*)d_in[4];
  const float* b_pb  = (const float*)d_in[5];
  const float* w_out = (const float*)d_in[6];
  const float* b_out = (const float*)d_in[7];
  float* out = (float*)d_out;

  char* ws = (char*)d_ws;
  __hip_bfloat16* qb      = (__hip_bfloat16*)(ws);                 // 16 MB
  __hip_bfloat16* kb      = (__hip_bfloat16*)(ws + 16777216);      // 16 MB
  __hip_bfloat16* vb      = (__hip_bfloat16*)(ws + 33554432);      // 16 MB [n][h][dh][l]
  __hip_bfloat16* msa_c   = (__hip_bfloat16*)(ws + 50331648);      // 16 MB
  __hip_bfloat16* ao      = (__hip_bfloat16*)(ws + 50331648);      // alias (msa dead after qkv)
  __hip_bfloat16* expb    = (__hip_bfloat16*)(ws + 67108864);      // 1 MB [h][q][k] bf16
  __hip_bfloat16* wqkv_t  = (__hip_bfloat16*)(ws + 71303168);      // 384 KB
  __hip_bfloat16* wout_t  = (__hip_bfloat16*)(ws + 71696384);      // 128 KB
  float*          msk     = (float*)(ws + 71827456);               // 128 KB

  mask_expand<<<32, 256, 0, stream>>>(mask, msk);
  cvt_bf16<<<1024, 256, 0, stream>>>(msa, msa_c, NN * LL * DD);
  transpose_cvt<<<dim3(24, 8), 256, 0, stream>>>(w_qkv, wqkv_t, 256, 768);
  transpose_cvt<<<dim3(8, 8), 256, 0, stream>>>(w_out, wout_t, 256, 256);

  qkv_gemm_mfma<<<dim3(256, 6), 256, 0, stream>>>(msa_c, wqkv_t, qb, kb, vb);
  pair_bias_kernel<<<2048, 256, 0, stream>>>(pair, w_pb, b_pb, expb);
  attn_mfma<<<1024, 256, 0, stream>>>(qb, kb, vb, expb, msk, ao);
  out_gemm_mfma<<<dim3(256, 2), 256, 0, stream>>>(ao, wout_t, b_out, out);
}

// Round 3
// 252.946 us; speedup vs baseline: 1.1930x; 1.1930x over previous
//
#include <hip/hip_runtime.h>
#include <hip/hip_bf16.h>

// Problem constants: B=1, N=128, L=256, D=256, P=128, H=8, DH=32
// Established: fp32 inputs, fp32 output; bf16-rounded ref, threshold 0.0289.
#define NN 128
#define LL 256
#define DD 256
#define PP 128
#define HH 8
#define DHH 32

typedef __bf16 bf16x8 __attribute__((ext_vector_type(8)));
typedef short s16x4 __attribute__((ext_vector_type(4)));
typedef float f32x4 __attribute__((ext_vector_type(4)));
typedef unsigned int u32x2 __attribute__((ext_vector_type(2)));

// async global->LDS, 16B per lane (dest = wave-uniform base + lane*16)
__device__ __forceinline__ void gload_lds16(const void* g, void* l) {
  __builtin_amdgcn_global_load_lds(
      (const __attribute__((address_space(1))) void*)g,
      (__attribute__((address_space(3))) void*)l, 16, 0, 0);
}

// ---------------------------------------------------------------------------
// fp32 -> bf16 bulk convert
// ---------------------------------------------------------------------------
__global__ __launch_bounds__(256) void cvt_bf16(
    const float* __restrict__ src, __hip_bfloat16* __restrict__ dst, int n) {
  for (int i = (blockIdx.x * 256 + threadIdx.x) * 4; i < n; i += gridDim.x * 1024) {
    float4 v = *(const float4*)(src + i);
    ushort4 o;
    o.x = __bfloat16_as_ushort(__float2bfloat16(v.x));
    o.y = __bfloat16_as_ushort(__float2bfloat16(v.y));
    o.z = __bfloat16_as_ushort(__float2bfloat16(v.z));
    o.w = __bfloat16_as_ushort(__float2bfloat16(v.w));
    *(ushort4*)(dst + i) = o;
  }
}

// ---------------------------------------------------------------------------
// transpose + convert: src [K][N] fp32 -> dst [N][K] bf16
// ---------------------------------------------------------------------------
__global__ __launch_bounds__(256) void transpose_cvt(
    const float* __restrict__ src, __hip_bfloat16* __restrict__ dst,
    int K, int N) {
  __shared__ float t[32][33];
  int n0 = blockIdx.x * 32, k0 = blockIdx.y * 32;
  int tx = threadIdx.x & 31, ty = threadIdx.x >> 5;
  for (int i = 0; i < 4; ++i) {
    int ky = ty + i * 8;
    t[ky][tx] = src[(size_t)(k0 + ky) * N + n0 + tx];
  }
  __syncthreads();
  for (int i = 0; i < 4; ++i) {
    int ny = ty + i * 8;
    dst[(size_t)(n0 + ny) * K + k0 + tx] = __float2bfloat16(t[tx][ny]);
  }
}

// ---------------------------------------------------------------------------
// mask normalization (int32 / int8 / bf16 / fp32 -> float 1.0/0.0), parallel
// ---------------------------------------------------------------------------
#define MODE_I32 0
#define MODE_I8 1
#define MODE_BF16 2
#define MODE_F32 3

__global__ __launch_bounds__(256) void mask_expand(
    const unsigned char* __restrict__ mraw, float* __restrict__ mout) {
  __shared__ int s_or1, s_or2, s_or3, s_max, s_mode;
  int tid = threadIdx.x;
  if (tid == 0) { s_or1 = 0; s_or2 = 0; s_or3 = 0; s_max = 0; }
  __syncthreads();
  int or1 = 0, or2 = 0, or3 = 0, mx = 0;
  for (int j = tid; j < 4096; j += 256) {
    int b = mraw[j];
    mx = mx > b ? mx : b;
    int r = j & 3;
    if (r == 1) or1 |= b;
    else if (r == 2) or2 |= b;
    else if (r == 3) or3 |= b;
  }
  atomicOr(&s_or1, or1); atomicOr(&s_or2, or2); atomicOr(&s_or3, or3);
  atomicMax(&s_max, mx);
  __syncthreads();
  if (tid == 0) {
    int mode;
    if (s_max <= 1) mode = ((s_or1 | s_or2 | s_or3) == 0) ? MODE_I32 : MODE_I8;
    else            mode = (s_or1 != 0) ? MODE_BF16 : MODE_F32;
    s_mode = mode;
  }
  __syncthreads();
  int mode = s_mode;
  int i0 = blockIdx.x * 1024;
  for (int i = i0 + tid; i < i0 + 1024; i += 256) {
    int v;
    if (mode == MODE_I32)       v = ((const int*)mraw)[i] != 0;
    else if (mode == MODE_I8)   v = mraw[i] != 0;
    else if (mode == MODE_BF16) v = ((const unsigned short*)mraw)[i] != 0;
    else                        v = ((const unsigned int*)mraw)[i] != 0;
    mout[i] = v ? 1.f : 0.f;
  }
}

// ---------------------------------------------------------------------------
// MFMA GEMM main loop (A [M][256] bf16, Bt [N][256] bf16 = B^T).
// 128x128 tile, BK=32, 4 waves of 64x64, 4x4 mfma_f32_16x16x32_bf16.
// Staging via global_load_lds width=16 (m97 structure).
// ---------------------------------------------------------------------------
#define GEMM_MAINLOOP(Aptr, Btptr)                                            \
  __shared__ __align__(16) __hip_bfloat16 Asm[128 * 32];                      \
  __shared__ __align__(16) __hip_bfloat16 Bsm[128 * 32];                      \
  int tid = threadIdx.x;                                                      \
  int lane = tid & 63;                                                        \
  int wv = tid >> 6;                                                          \
  int wm = (wv >> 1) * 64, wn = (wv & 1) * 64;                                \
  int lr = lane & 15, quad = lane >> 4;                                       \
  int bm = blockIdx.x, bn = blockIdx.y;                                       \
  f32x4 acc[4][4];                                                            \
  for (int i = 0; i < 4; ++i)                                                 \
    for (int j = 0; j < 4; ++j) acc[i][j] = (f32x4){0.f, 0.f, 0.f, 0.f};      \
  for (int ks = 0; ks < 8; ++ks) {                                            \
    int k0 = ks * 32;                                                         \
    if (ks) __syncthreads();                                                  \
    for (int i = 0; i < 2; ++i) {                                             \
      int c = tid + i * 256;                                                  \
      int row = c >> 2, cc = c & 3;                                           \
      int ldsbase = (wv * 64 + i * 256) * 8; /* elements; wave-uniform */     \
      gload_lds16(Aptr + ((size_t)(bm * 128 + row)) * 256 + k0 + cc * 8,      \
                  Asm + ldsbase);                                             \
      gload_lds16(Btptr + ((size_t)(bn * 128 + row)) * 256 + k0 + cc * 8,     \
                  Bsm + ldsbase);                                             \
    }                                                                         \
    __syncthreads();                                                          \
    bf16x8 af[4], bfr[4];                                                     \
    for (int mi = 0; mi < 4; ++mi)                                            \
      af[mi] = *(const bf16x8*)&Asm[(wm + mi * 16 + lr) * 32 + quad * 8];     \
    for (int ni = 0; ni < 4; ++ni)                                            \
      bfr[ni] = *(const bf16x8*)&Bsm[(wn + ni * 16 + lr) * 32 + quad * 8];    \
    for (int mi = 0; mi < 4; ++mi)                                            \
      for (int ni = 0; ni < 4; ++ni)                                          \
        acc[mi][ni] = __builtin_amdgcn_mfma_f32_16x16x32_bf16(                \
            af[mi], bfr[ni], acc[mi][ni], 0, 0, 0);                           \
  }

// QKV: q,k -> [n][h][l][dh]; v -> [n][h][dh][l] (transposed for attention).
__global__ __launch_bounds__(256) void qkv_gemm_mfma(
    const __hip_bfloat16* __restrict__ A,
    const __hip_bfloat16* __restrict__ Bt,
    __hip_bfloat16* __restrict__ qb,
    __hip_bfloat16* __restrict__ kb,
    __hip_bfloat16* __restrict__ vb) {
  GEMM_MAINLOOP(A, Bt)
  for (int mi = 0; mi < 4; ++mi) {
    for (int ni = 0; ni < 4; ++ni) {
      int gcol = bn * 128 + wn + ni * 16 + lr;
      int t = gcol >> 8, rem = gcol & 255;
      int h = rem >> 5, dh = rem & 31;
      for (int r = 0; r < 4; ++r) {
        int grow = bm * 128 + wm + mi * 16 + quad * 4 + r;
        int n = grow >> 8, l = grow & 255;
        __hip_bfloat16 val = __float2bfloat16(acc[mi][ni][r]);
        if (t == 0)
          qb[(size_t)(((n * HH + h) * LL + l)) * DHH + dh] = val;
        else if (t == 1)
          kb[(size_t)(((n * HH + h) * LL + l)) * DHH + dh] = val;
        else
          vb[(size_t)(((n * HH + h) * DHH + dh)) * LL + l] = val;
      }
    }
  }
}

__global__ __launch_bounds__(256) void out_gemm_mfma(
    const __hip_bfloat16* __restrict__ A,
    const __hip_bfloat16* __restrict__ Bt,
    const float* __restrict__ bout,
    float* __restrict__ C) {
  GEMM_MAINLOOP(A, Bt)
  for (int mi = 0; mi < 4; ++mi) {
    for (int ni = 0; ni < 4; ++ni) {
      int gcol = bn * 128 + wn + ni * 16 + lr;
      float bo = bout[gcol];
      for (int r = 0; r < 4; ++r) {
        int grow = bm * 128 + wm + mi * 16 + quad * 4 + r;
        C[(size_t)grow * 256 + gcol] = acc[mi][ni][r] + bo;
      }
    }
  }
}

// ---------------------------------------------------------------------------
// pair bias -> expb[h][q][k] = exp(pair@w_pb + b_pb - 12) as bf16.
// ---------------------------------------------------------------------------
__global__ __launch_bounds__(256) void pair_bias_kernel(
    const float* __restrict__ pair,
    const float* __restrict__ w_pb,
    const float* __restrict__ b_pb,
    __hip_bfloat16* __restrict__ expb) {
  __shared__ float wp[128][9];
  __shared__ float rows[32][129];
  int tid = threadIdx.x;
  for (int i = 0; i < 4; ++i) {
    int e = tid + i * 256;
    wp[e >> 3][e & 7] = w_pb[e];
  }
  int row0 = blockIdx.x * 32;
  const float* src = pair + (size_t)row0 * PP;
  for (int i = 0; i < 16; ++i) {
    int e = tid + i * 256;
    int r = e >> 7, c = e & 127;
    rows[r][c] = src[r * 128 + c];
  }
  __syncthreads();
  int h = tid >> 5, rl = tid & 31;
  float acc = b_pb[h] - 12.0f;
  for (int p = 0; p < 128; ++p)
    acc += rows[rl][p] * wp[p][h];
  int row = row0 + rl;
  int i = row >> 8, j = row & 255;
  expb[((size_t)(h * LL + i)) * LL + j] = __float2bfloat16(__expf(acc));
}

// ---------------------------------------------------------------------------
// Flash-style MFMA attention: zero LDS, swapped QK^T, fixed-shift softmax,
// pre-exponentiated bf16 bias stream.
//
// Round-3: register double-buffering with GUARANTEED-STATIC buffer selection.
// Round-2's #pragma unroll kt-loop did not fully unroll -> cur/nxt became
// runtime -> buffers spilled to scratch (WRITE_SIZE 16->179 MB, 2x dur).
// Here all 16 (kt,mi) phases are macro-expanded straight-line; buffers are
// chosen by token (bkA/bkB, ebE/ebO), arrays only literal-indexed. K/V/mask
// prefetch one full kt ahead (~900cy HBM latency covered by ~4 phases of
// compute); expb one mi-phase ahead (L2-resident). __launch_bounds__(256,2)
// allows the ~220-VGPR working set without spill.
// ---------------------------------------------------------------------------
__global__ __launch_bounds__(256, 2) void attn_mfma(
    const __hip_bfloat16* __restrict__ qb,
    const __hip_bfloat16* __restrict__ kb,
    const __hip_bfloat16* __restrict__ vbt,
    const __hip_bfloat16* __restrict__ expb,  // [h][q][k] = exp(bias-12) bf16
    const float* __restrict__ maskf,          // [n][k] 1.0/0.0
    __hip_bfloat16* __restrict__ ao) {
  int bx = blockIdx.x;
  int h = bx >> 7, n = bx & 127;
  int nh = n * HH + h;
  int tid = threadIdx.x, lane = tid & 63, wv = tid >> 6;
  int lr = lane & 15, quad = lane >> 4;
  int wm = wv * 64;
  size_t base = (size_t)nh * (LL * DHH);

  const __hip_bfloat16* qp = qb + base;
  const __hip_bfloat16* kp = kb + base;
  const __hip_bfloat16* vp = vbt + base;
  const __hip_bfloat16* ep = expb + (size_t)h * LL * LL;
  const float* mrow = maskf + n * LL;

  const float cs = 0.17677669529663687f * 1.4426950408889634f;  // scale*log2e

  // Q fragments (row q = wm+mi*16+lr, dh = quad*8..+7); B-operand of QK^T.
  bf16x8 aq[4];
#pragma unroll
  for (int mi = 0; mi < 4; ++mi)
    aq[mi] = *(const bf16x8*)(qp + (size_t)(wm + mi * 16 + lr) * DHH + quad * 8);

  // double-buffered kt-level operands (A/B), eb ping-pong (E/O).
  bf16x8 bkA[4], bkB[4];
  s16x4 avA[4][2], avB[4][2];
  f32x4 mwA[4], mwB[4];
  uint2 ebE[4], ebO[4];

#define LOADKT(S, KT)                                                          \
  {                                                                            \
    const int j0_ = (KT) * 64;                                                 \
    _Pragma("unroll") for (int nj = 0; nj < 4; ++nj)                           \
        bk##S[nj] =                                                            \
        *(const bf16x8*)(kp + (size_t)(j0_ + nj * 16 + lr) * DHH + quad * 8);  \
    _Pragma("unroll") for (int nj = 0; nj < 4; ++nj) {                         \
      av##S[nj][0] = *(const s16x4*)(vp + (size_t)lr * LL +                    \
                                     j0_ + nj * 16 + quad * 4);                \
      av##S[nj][1] = *(const s16x4*)(vp + (size_t)(16 + lr) * LL +             \
                                     j0_ + nj * 16 + quad * 4);                \
    }                                                                          \
    _Pragma("unroll") for (int nj = 0; nj < 4; ++nj)                           \
        mw##S[nj] = *(const f32x4*)(mrow + j0_ + nj * 16 + quad * 4);          \
  }

#define LOADEB(S, KT, MI)                                                      \
  {                                                                            \
    const __hip_bfloat16* er_ =                                                \
        ep + (size_t)(wm + (MI) * 16 + lr) * LL + (KT) * 64;                   \
    _Pragma("unroll") for (int nj = 0; nj < 4; ++nj)                           \
        eb##S[nj] = *(const uint2*)(er_ + nj * 16 + quad * 4);                 \
  }

// One (kt,mi) phase. C = kt buffer token, EC/EN = eb consume/prefetch tokens,
// (NKT,NMI) = phase to prefetch into ebEN, DOPF = prefetch enable (literal).
#define MI_PHASE(KT, MI, C, EC, EN, NKT, NMI, DOPF)                            \
  {                                                                            \
    if (DOPF) LOADEB(EN, NKT, NMI);                                            \
    f32x4 s_[4];                                                               \
    _Pragma("unroll") for (int nj = 0; nj < 4; ++nj)                           \
        s_[nj] = __builtin_amdgcn_mfma_f32_16x16x32_bf16(                      \
            bk##C[nj], aq[MI], (f32x4){0.f, 0.f, 0.f, 0.f}, 0, 0, 0);          \
    _Pragma("unroll") for (int nj = 0; nj < 4; ++nj) {                         \
      uint2 e_ = eb##EC[nj];                                                   \
      f32x4 m4_ = mw##C[nj];                                                   \
      float em0_ = __uint_as_float(e_.x << 16) * m4_[0];                       \
      float em1_ = __uint_as_float(e_.x & 0xffff0000u) * m4_[1];               \
      float em2_ = __uint_as_float(e_.y << 16) * m4_[2];                       \
      float em3_ = __uint_as_float(e_.y & 0xffff0000u) * m4_[3];               \
      float p0_ = exp2f(s_[nj][0] * cs) * em0_;                                \
      float p1_ = exp2f(s_[nj][1] * cs) * em1_;                                \
      float p2_ = exp2f(s_[nj][2] * cs) * em2_;                                \
      float p3_ = exp2f(s_[nj][3] * cs) * em3_;                                \
      lsum[MI] += (p0_ + p1_) + (p2_ + p3_);                                   \
      unsigned lo_ =                                                           \
          ((unsigned)__bfloat16_as_ushort(__float2bfloat16(p1_)) << 16) |      \
          (unsigned)__bfloat16_as_ushort(__float2bfloat16(p0_));               \
      unsigned hi_ =                                                           \
          ((unsigned)__bfloat16_as_ushort(__float2bfloat16(p3_)) << 16) |      \
          (unsigned)__bfloat16_as_ushort(__float2bfloat16(p2_));               \
      u32x2 pu_ = {lo_, hi_};                                                  \
      s16x4 pb_ = __builtin_bit_cast(s16x4, pu_);                              \
      o_acc[MI][0] = __builtin_amdgcn_mfma_f32_16x16x16bf16_1k(                \
          av##C[nj][0], pb_, o_acc[MI][0], 0, 0, 0);                           \
      o_acc[MI][1] = __builtin_amdgcn_mfma_f32_16x16x16bf16_1k(                \
          av##C[nj][1], pb_, o_acc[MI][1], 0, 0, 0);                           \
    }                                                                          \
  }

// A kt phase: prefetch next kt's K/V/mask into N, then 4 mi sub-phases.
// eb parity: phase g = kt*4+mi, even->E, odd->O (kt*4 always even).
#define KT_PHASE(KT, C, N, LAST)                                               \
  {                                                                            \
    if (!(LAST)) LOADKT(N, (KT) + 1);                                          \
    MI_PHASE(KT, 0, C, E, O, KT, 1, 1)                                         \
    MI_PHASE(KT, 1, C, O, E, KT, 2, 1)                                         \
    MI_PHASE(KT, 2, C, E, O, KT, 3, 1)                                         \
    MI_PHASE(KT, 3, C, O, E, (KT) + 1 > 3 ? 0 : (KT) + 1, 0, !(LAST))          \
  }

  float lsum[4] = {0.f, 0.f, 0.f, 0.f};
  f32x4 o_acc[4][2];
#pragma unroll
  for (int mi = 0; mi < 4; ++mi)
#pragma unroll
    for (int no = 0; no < 2; ++no) o_acc[mi][no] = (f32x4){0.f, 0.f, 0.f, 0.f};

  LOADKT(A, 0)
  LOADEB(E, 0, 0)

  KT_PHASE(0, A, B, 0)
  KT_PHASE(1, B, A, 0)
  KT_PHASE(2, A, B, 0)
  KT_PHASE(3, B, A, 1)

#undef LOADKT
#undef LOADEB
#undef MI_PHASE
#undef KT_PHASE

  // epilogue: O^T tile (row dh = no*16+quad*4+r, col q = wm+mi*16+lr).
#pragma unroll
  for (int mi = 0; mi < 4; ++mi) {
    float ls = lsum[mi];
    ls += __shfl_xor(ls, 16);
    ls += __shfl_xor(ls, 32);
    float inv = (ls > 0.f) ? 1.f / ls : 0.f;
    int q = wm + mi * 16 + lr;
#pragma unroll
    for (int no = 0; no < 2; ++no) {
      f32x4 o = o_acc[mi][no];
      ushort4 w;
      w.x = __bfloat16_as_ushort(__float2bfloat16(o[0] * inv));
      w.y = __bfloat16_as_ushort(__float2bfloat16(o[1] * inv));
      w.z = __bfloat16_as_ushort(__float2bfloat16(o[2] * inv));
      w.w = __bfloat16_as_ushort(__float2bfloat16(o[3] * inv));
      *(ushort4*)(ao + (size_t)n * (LL * DD) + (size_t)q * DD +
                  h * DHH + no * 16 + quad * 4) = w;
    }
  }
}

extern "C" void kernel_launch(void* const* d_in, const int* in_sizes, int n_in,
                              void* d_out, int out_size, void* d_ws, size_t ws_size,
                              hipStream_t stream) {
  const float* msa   = (const float*)d_in[0];
  const float* pair  = (const float*)d_in[1];
  const unsigned char* mask = (const unsigned char*)d_in[2];
  const float* w_qkv = (const float*)d_in[3];
  const float* w_pb  = (const float*)d_in[4];
  const float* b_pb  = (const float*)d_in[5];
  const float* w_out = (const float*)d_in[6];
  const float* b_out = (const float*)d_in[7];
  float* out = (float*)d_out;

  char* ws = (char*)d_ws;
  __hip_bfloat16* qb      = (__hip_bfloat16*)(ws);                 // 16 MB
  __hip_bfloat16* kb      = (__hip_bfloat16*)(ws + 16777216);      // 16 MB
  __hip_bfloat16* vb      = (__hip_bfloat16*)(ws + 33554432);      // 16 MB [n][h][dh][l]
  __hip_bfloat16* msa_c   = (__hip_bfloat16*)(ws + 50331648);      // 16 MB
  __hip_bfloat16* ao      = (__hip_bfloat16*)(ws + 50331648);      // alias (msa dead after qkv)
  __hip_bfloat16* expb    = (__hip_bfloat16*)(ws + 67108864);      // 1 MB [h][q][k] bf16
  __hip_bfloat16* wqkv_t  = (__hip_bfloat16*)(ws + 71303168);      // 384 KB
  __hip_bfloat16* wout_t  = (__hip_bfloat16*)(ws + 71696384);      // 128 KB
  float*          msk     = (float*)(ws + 71827456);               // 128 KB

  mask_expand<<<32, 256, 0, stream>>>(mask, msk);
  cvt_bf16<<<1024, 256, 0, stream>>>(msa, msa_c, NN * LL * DD);
  transpose_cvt<<<dim3(24, 8), 256, 0, stream>>>(w_qkv, wqkv_t, 256, 768);
  transpose_cvt<<<dim3(8, 8), 256, 0, stream>>>(w_out, wout_t, 256, 256);

  qkv_gemm_mfma<<<dim3(256, 6), 256, 0, stream>>>(msa_c, wqkv_t, qb, kb, vb);
  pair_bias_kernel<<<2048, 256, 0, stream>>>(pair, w_pb, b_pb, expb);
  attn_mfma<<<1024, 256, 0, stream>>>(qb, kb, vb, expb, msk, ao);
  out_gemm_mfma<<<dim3(256, 2), 256, 0, stream>>>(ao, wout_t, b_out, out);
}

// Round 4
// 241.663 us; speedup vs baseline: 1.2487x; 1.0467x over previous
//
#include <hip/hip_runtime.h>
#include <hip/hip_bf16.h>

// Problem constants: B=1, N=128, L=256, D=256, P=128, H=8, DH=32
// Established: fp32 inputs, fp32 output; bf16-rounded ref, threshold 0.0289.
#define NN 128
#define LL 256
#define DD 256
#define PP 128
#define HH 8
#define DHH 32

typedef __bf16 bf16x8 __attribute__((ext_vector_type(8)));
typedef short s16x4 __attribute__((ext_vector_type(4)));
typedef short s16x8 __attribute__((ext_vector_type(8)));
typedef float f32x4 __attribute__((ext_vector_type(4)));
typedef unsigned int u32x2 __attribute__((ext_vector_type(2)));

// k' permutation: within each 64-block, swap bits[5:4] (nj) with bits[3:2]
// (quad) so that a lane's MFMA-fragment elements (nj 0..3, r 0..3 at fixed
// quad) become CONTIGUOUS 16 values. Self-inverse. Applied at the producers
// (free index remap) for expb, vb, msk.
__device__ __forceinline__ int permk(int k) {
  return (k & 0xC3) | ((k & 0x30) >> 2) | ((k & 0x0C) << 2);
}

// async global->LDS, 16B per lane (dest = wave-uniform base + lane*16)
__device__ __forceinline__ void gload_lds16(const void* g, void* l) {
  __builtin_amdgcn_global_load_lds(
      (const __attribute__((address_space(1))) void*)g,
      (__attribute__((address_space(3))) void*)l, 16, 0, 0);
}

// ---------------------------------------------------------------------------
// fp32 -> bf16 bulk convert
// ---------------------------------------------------------------------------
__global__ __launch_bounds__(256) void cvt_bf16(
    const float* __restrict__ src, __hip_bfloat16* __restrict__ dst, int n) {
  for (int i = (blockIdx.x * 256 + threadIdx.x) * 4; i < n; i += gridDim.x * 1024) {
    float4 v = *(const float4*)(src + i);
    ushort4 o;
    o.x = __bfloat16_as_ushort(__float2bfloat16(v.x));
    o.y = __bfloat16_as_ushort(__float2bfloat16(v.y));
    o.z = __bfloat16_as_ushort(__float2bfloat16(v.z));
    o.w = __bfloat16_as_ushort(__float2bfloat16(v.w));
    *(ushort4*)(dst + i) = o;
  }
}

// ---------------------------------------------------------------------------
// transpose + convert: src [K][N] fp32 -> dst [N][K] bf16
// ---------------------------------------------------------------------------
__global__ __launch_bounds__(256) void transpose_cvt(
    const float* __restrict__ src, __hip_bfloat16* __restrict__ dst,
    int K, int N) {
  __shared__ float t[32][33];
  int n0 = blockIdx.x * 32, k0 = blockIdx.y * 32;
  int tx = threadIdx.x & 31, ty = threadIdx.x >> 5;
  for (int i = 0; i < 4; ++i) {
    int ky = ty + i * 8;
    t[ky][tx] = src[(size_t)(k0 + ky) * N + n0 + tx];
  }
  __syncthreads();
  for (int i = 0; i < 4; ++i) {
    int ny = ty + i * 8;
    dst[(size_t)(n0 + ny) * K + k0 + tx] = __float2bfloat16(t[tx][ny]);
  }
}

// ---------------------------------------------------------------------------
// mask normalization -> float 1.0/0.0 at k'-PERMUTED index
// ---------------------------------------------------------------------------
#define MODE_I32 0
#define MODE_I8 1
#define MODE_BF16 2
#define MODE_F32 3

__global__ __launch_bounds__(256) void mask_expand(
    const unsigned char* __restrict__ mraw, float* __restrict__ mout) {
  __shared__ int s_or1, s_or2, s_or3, s_max, s_mode;
  int tid = threadIdx.x;
  if (tid == 0) { s_or1 = 0; s_or2 = 0; s_or3 = 0; s_max = 0; }
  __syncthreads();
  int or1 = 0, or2 = 0, or3 = 0, mx = 0;
  for (int j = tid; j < 4096; j += 256) {
    int b = mraw[j];
    mx = mx > b ? mx : b;
    int r = j & 3;
    if (r == 1) or1 |= b;
    else if (r == 2) or2 |= b;
    else if (r == 3) or3 |= b;
  }
  atomicOr(&s_or1, or1); atomicOr(&s_or2, or2); atomicOr(&s_or3, or3);
  atomicMax(&s_max, mx);
  __syncthreads();
  if (tid == 0) {
    int mode;
    if (s_max <= 1) mode = ((s_or1 | s_or2 | s_or3) == 0) ? MODE_I32 : MODE_I8;
    else            mode = (s_or1 != 0) ? MODE_BF16 : MODE_F32;
    s_mode = mode;
  }
  __syncthreads();
  int mode = s_mode;
  int i0 = blockIdx.x * 1024;
  for (int i = i0 + tid; i < i0 + 1024; i += 256) {
    int v;
    if (mode == MODE_I32)       v = ((const int*)mraw)[i] != 0;
    else if (mode == MODE_I8)   v = mraw[i] != 0;
    else if (mode == MODE_BF16) v = ((const unsigned short*)mraw)[i] != 0;
    else                        v = ((const unsigned int*)mraw)[i] != 0;
    mout[(i & ~255) | permk(i & 255)] = v ? 1.f : 0.f;
  }
}

// ---------------------------------------------------------------------------
// MFMA GEMM main loop (A [M][256] bf16, Bt [N][256] bf16 = B^T).
// 128x128 tile, BK=32, 4 waves of 64x64, 4x4 mfma_f32_16x16x32_bf16.
// Staging via global_load_lds width=16 (m97 structure).
// ---------------------------------------------------------------------------
#define GEMM_MAINLOOP(Aptr, Btptr)                                            \
  __shared__ __align__(16) __hip_bfloat16 Asm[128 * 32];                      \
  __shared__ __align__(16) __hip_bfloat16 Bsm[128 * 32];                      \
  int tid = threadIdx.x;                                                      \
  int lane = tid & 63;                                                        \
  int wv = tid >> 6;                                                          \
  int wm = (wv >> 1) * 64, wn = (wv & 1) * 64;                                \
  int lr = lane & 15, quad = lane >> 4;                                       \
  int bm = blockIdx.x, bn = blockIdx.y;                                       \
  f32x4 acc[4][4];                                                            \
  for (int i = 0; i < 4; ++i)                                                 \
    for (int j = 0; j < 4; ++j) acc[i][j] = (f32x4){0.f, 0.f, 0.f, 0.f};      \
  for (int ks = 0; ks < 8; ++ks) {                                            \
    int k0 = ks * 32;                                                         \
    if (ks) __syncthreads();                                                  \
    for (int i = 0; i < 2; ++i) {                                             \
      int c = tid + i * 256;                                                  \
      int row = c >> 2, cc = c & 3;                                           \
      int ldsbase = (wv * 64 + i * 256) * 8; /* elements; wave-uniform */     \
      gload_lds16(Aptr + ((size_t)(bm * 128 + row)) * 256 + k0 + cc * 8,      \
                  Asm + ldsbase);                                             \
      gload_lds16(Btptr + ((size_t)(bn * 128 + row)) * 256 + k0 + cc * 8,     \
                  Bsm + ldsbase);                                             \
    }                                                                         \
    __syncthreads();                                                          \
    bf16x8 af[4], bfr[4];                                                     \
    for (int mi = 0; mi < 4; ++mi)                                            \
      af[mi] = *(const bf16x8*)&Asm[(wm + mi * 16 + lr) * 32 + quad * 8];     \
    for (int ni = 0; ni < 4; ++ni)                                            \
      bfr[ni] = *(const bf16x8*)&Bsm[(wn + ni * 16 + lr) * 32 + quad * 8];    \
    for (int mi = 0; mi < 4; ++mi)                                            \
      for (int ni = 0; ni < 4; ++ni)                                          \
        acc[mi][ni] = __builtin_amdgcn_mfma_f32_16x16x32_bf16(                \
            af[mi], bfr[ni], acc[mi][ni], 0, 0, 0);                           \
  }

// QKV: q,k -> [n][h][l][dh]; v -> [n][h][dh][l'] (transposed + k'-permuted).
__global__ __launch_bounds__(256) void qkv_gemm_mfma(
    const __hip_bfloat16* __restrict__ A,
    const __hip_bfloat16* __restrict__ Bt,
    __hip_bfloat16* __restrict__ qb,
    __hip_bfloat16* __restrict__ kb,
    __hip_bfloat16* __restrict__ vb) {
  GEMM_MAINLOOP(A, Bt)
  for (int mi = 0; mi < 4; ++mi) {
    for (int ni = 0; ni < 4; ++ni) {
      int gcol = bn * 128 + wn + ni * 16 + lr;
      int t = gcol >> 8, rem = gcol & 255;
      int h = rem >> 5, dh = rem & 31;
      for (int r = 0; r < 4; ++r) {
        int grow = bm * 128 + wm + mi * 16 + quad * 4 + r;
        int n = grow >> 8, l = grow & 255;
        __hip_bfloat16 val = __float2bfloat16(acc[mi][ni][r]);
        if (t == 0)
          qb[(size_t)(((n * HH + h) * LL + l)) * DHH + dh] = val;
        else if (t == 1)
          kb[(size_t)(((n * HH + h) * LL + l)) * DHH + dh] = val;
        else
          vb[(size_t)(((n * HH + h) * DHH + dh)) * LL + permk(l)] = val;
      }
    }
  }
}

__global__ __launch_bounds__(256) void out_gemm_mfma(
    const __hip_bfloat16* __restrict__ A,
    const __hip_bfloat16* __restrict__ Bt,
    const float* __restrict__ bout,
    float* __restrict__ C) {
  GEMM_MAINLOOP(A, Bt)
  for (int mi = 0; mi < 4; ++mi) {
    for (int ni = 0; ni < 4; ++ni) {
      int gcol = bn * 128 + wn + ni * 16 + lr;
      float bo = bout[gcol];
      for (int r = 0; r < 4; ++r) {
        int grow = bm * 128 + wm + mi * 16 + quad * 4 + r;
        C[(size_t)grow * 256 + gcol] = acc[mi][ni][r] + bo;
      }
    }
  }
}

// ---------------------------------------------------------------------------
// pair bias -> expb[h][q][k'] = exp(pair@w_pb + b_pb - 12) bf16, k'-permuted.
// ---------------------------------------------------------------------------
__global__ __launch_bounds__(256) void pair_bias_kernel(
    const float* __restrict__ pair,
    const float* __restrict__ w_pb,
    const float* __restrict__ b_pb,
    __hip_bfloat16* __restrict__ expb) {
  __shared__ float wp[128][9];
  __shared__ float rows[32][129];
  int tid = threadIdx.x;
  for (int i = 0; i < 4; ++i) {
    int e = tid + i * 256;
    wp[e >> 3][e & 7] = w_pb[e];
  }
  int row0 = blockIdx.x * 32;
  const float* src = pair + (size_t)row0 * PP;
  for (int i = 0; i < 16; ++i) {
    int e = tid + i * 256;
    int r = e >> 7, c = e & 127;
    rows[r][c] = src[r * 128 + c];
  }
  __syncthreads();
  int h = tid >> 5, rl = tid & 31;
  float acc = b_pb[h] - 12.0f;
  for (int p = 0; p < 128; ++p)
    acc += rows[rl][p] * wp[p][h];
  int row = row0 + rl;
  int i = row >> 8, j = row & 255;
  expb[((size_t)(h * LL + i)) * LL + permk(j)] = __float2bfloat16(__expf(acc));
}

// ---------------------------------------------------------------------------
// Flash-style MFMA attention: zero LDS, swapped QK^T, fixed-shift softmax,
// pre-exponentiated bf16 bias, k'-permuted operand layouts.
//
// Round-4: r0-r3 all pinned at ~59us with ~132 VMEM loads/wave -> theory:
// wave advances ~1 memory-latency per load because vmcnt is an IN-ORDER
// counter (consuming a late-issued L2 load waits for all older in-flight
// HBM loads). Fix: (a) k'-permuted layouts make eb/V fragments contiguous
// 32B -> loads/wave 132->84, all 16B-wide; (b) per-kt issue order
// [eb, mask, then K/V(kt+1)] so every consume is strictly issue-ordered:
// eb consumes need only their own ~L2 latency, K/V consumes happen a full
// kt after issue. eb/mw single-buffered (within-kt), K/V double-buffered
// via static tokens (A/B), everything literal-indexed (no scratch).
// ---------------------------------------------------------------------------
__global__ __launch_bounds__(256, 2) void attn_mfma(
    const __hip_bfloat16* __restrict__ qb,
    const __hip_bfloat16* __restrict__ kb,
    const __hip_bfloat16* __restrict__ vbt,   // [n][h][dh][k'] bf16
    const __hip_bfloat16* __restrict__ expb,  // [h][q][k'] = exp(bias-12) bf16
    const float* __restrict__ maskf,          // [n][k'] 1.0/0.0
    __hip_bfloat16* __restrict__ ao) {
  int bx = blockIdx.x;
  int h = bx >> 7, n = bx & 127;
  int nh = n * HH + h;
  int tid = threadIdx.x, lane = tid & 63, wv = tid >> 6;
  int lr = lane & 15, quad = lane >> 4;
  int wm = wv * 64;
  size_t base = (size_t)nh * (LL * DHH);

  const __hip_bfloat16* qp = qb + base;
  const __hip_bfloat16* kp = kb + base;
  const __hip_bfloat16* vp = vbt + base;
  const __hip_bfloat16* ep = expb + (size_t)h * LL * LL;
  const float* mrow = maskf + n * LL;

  const float cs = 0.17677669529663687f * 1.4426950408889634f;  // scale*log2e

  // Q fragments (row q = wm+mi*16+lr, dh = quad*8..+7); B-operand of QK^T.
  bf16x8 aq[4];
#pragma unroll
  for (int mi = 0; mi < 4; ++mi)
    aq[mi] = *(const bf16x8*)(qp + (size_t)(wm + mi * 16 + lr) * DHH + quad * 8);

  // K double-buffered (A/B tokens); V likewise (contig 16B halves a/b per no).
  bf16x8 bkA[4], bkB[4];
  s16x8 avA0a, avA0b, avA1a, avA1b;
  s16x8 avB0a, avB0b, avB1a, avB1b;
  // eb: all 4 mi of the CURRENT kt, single-buffered (2x16B per mi).
  uint4 e0a, e0b, e1a, e1b, e2a, e2b, e3a, e3b;
  // mask multipliers for current kt (k'-contiguous).
  f32x4 mw0, mw1, mw2, mw3;

#define LOADKT(S, KT)                                                          \
  {                                                                            \
    const int j0_ = (KT) * 64;                                                 \
    _Pragma("unroll") for (int nj = 0; nj < 4; ++nj)                           \
        bk##S[nj] =                                                            \
        *(const bf16x8*)(kp + (size_t)(j0_ + nj * 16 + lr) * DHH + quad * 8);  \
    av##S##0a = *(const s16x8*)(vp + (size_t)lr * LL + j0_ + quad * 16);       \
    av##S##0b = *(const s16x8*)(vp + (size_t)lr * LL + j0_ + quad * 16 + 8);   \
    av##S##1a = *(const s16x8*)(vp + (size_t)(16 + lr) * LL + j0_ + quad * 16);\
    av##S##1b =                                                                \
        *(const s16x8*)(vp + (size_t)(16 + lr) * LL + j0_ + quad * 16 + 8);    \
  }

#define LOADEB_ALL(KT)                                                         \
  {                                                                            \
    const int j0_ = (KT) * 64;                                                 \
    e0a = *(const uint4*)(ep + (size_t)(wm + 0 + lr) * LL + j0_ + quad * 16);  \
    e0b = *(const uint4*)(ep + (size_t)(wm + 0 + lr) * LL + j0_ + quad * 16 + 8);\
    e1a = *(const uint4*)(ep + (size_t)(wm + 16 + lr) * LL + j0_ + quad * 16); \
    e1b = *(const uint4*)(ep + (size_t)(wm + 16 + lr) * LL + j0_ + quad * 16 + 8);\
    e2a = *(const uint4*)(ep + (size_t)(wm + 32 + lr) * LL + j0_ + quad * 16); \
    e2b = *(const uint4*)(ep + (size_t)(wm + 32 + lr) * LL + j0_ + quad * 16 + 8);\
    e3a = *(const uint4*)(ep + (size_t)(wm + 48 + lr) * LL + j0_ + quad * 16); \
    e3b = *(const uint4*)(ep + (size_t)(wm + 48 + lr) * LL + j0_ + quad * 16 + 8);\
  }

#define LOADMW(KT)                                                             \
  {                                                                            \
    const int j0_ = (KT) * 64;                                                 \
    mw0 = *(const f32x4*)(mrow + j0_ + quad * 16 + 0);                         \
    mw1 = *(const f32x4*)(mrow + j0_ + quad * 16 + 4);                         \
    mw2 = *(const f32x4*)(mrow + j0_ + quad * 16 + 8);                         \
    mw3 = *(const f32x4*)(mrow + j0_ + quad * 16 + 12);                        \
  }

// One nj step of one (kt,mi) phase. EX/EY = the two eb dwords for this nj,
// AV0/AV1 = 16B V fragments (no=0,1), LO = element offset (0 or 4).
#define NJ_STEP(C, MI, NJ, EX, EY, AV0, AV1, LO)                               \
  {                                                                            \
    f32x4 s_ = __builtin_amdgcn_mfma_f32_16x16x32_bf16(                        \
        bk##C[NJ], aq[MI], (f32x4){0.f, 0.f, 0.f, 0.f}, 0, 0, 0);              \
    float em0_ = __uint_as_float((EX) << 16) * mw##NJ[0];                      \
    float em1_ = __uint_as_float((EX) & 0xffff0000u) * mw##NJ[1];              \
    float em2_ = __uint_as_float((EY) << 16) * mw##NJ[2];                      \
    float em3_ = __uint_as_float((EY) & 0xffff0000u) * mw##NJ[3];              \
    float p0_ = exp2f(s_[0] * cs) * em0_;                                      \
    float p1_ = exp2f(s_[1] * cs) * em1_;                                      \
    float p2_ = exp2f(s_[2] * cs) * em2_;                                      \
    float p3_ = exp2f(s_[3] * cs) * em3_;                                      \
    lsum[MI] += (p0_ + p1_) + (p2_ + p3_);                                     \
    unsigned lo_ =                                                             \
        ((unsigned)__bfloat16_as_ushort(__float2bfloat16(p1_)) << 16) |        \
        (unsigned)__bfloat16_as_ushort(__float2bfloat16(p0_));                 \
    unsigned hi_ =                                                             \
        ((unsigned)__bfloat16_as_ushort(__float2bfloat16(p3_)) << 16) |        \
        (unsigned)__bfloat16_as_ushort(__float2bfloat16(p2_));                 \
    u32x2 pu_ = {lo_, hi_};                                                    \
    s16x4 pb_ = __builtin_bit_cast(s16x4, pu_);                                \
    s16x4 a0_ = __builtin_shufflevector(AV0, AV0, LO, LO + 1, LO + 2, LO + 3); \
    s16x4 a1_ = __builtin_shufflevector(AV1, AV1, LO, LO + 1, LO + 2, LO + 3); \
    o_acc[MI][0] = __builtin_amdgcn_mfma_f32_16x16x16bf16_1k(                  \
        a0_, pb_, o_acc[MI][0], 0, 0, 0);                                      \
    o_acc[MI][1] = __builtin_amdgcn_mfma_f32_16x16x16bf16_1k(                  \
        a1_, pb_, o_acc[MI][1], 0, 0, 0);                                      \
  }

#define MI_PHASE(MI, C, EA, EB_)                                               \
  {                                                                            \
    NJ_STEP(C, MI, 0, EA.x, EA.y, av##C##0a, av##C##1a, 0)                     \
    NJ_STEP(C, MI, 1, EA.z, EA.w, av##C##0a, av##C##1a, 4)                     \
    NJ_STEP(C, MI, 2, EB_.x, EB_.y, av##C##0b, av##C##1b, 0)                   \
    NJ_STEP(C, MI, 3, EB_.z, EB_.w, av##C##0b, av##C##1b, 4)                   \
  }

// Issue order per kt: eb (needed in ~1 phase, L2) first, then mask, then the
// NEXT kt's K/V (HBM, consumed a full kt later). Consumption is strictly in
// issue order -> compiler's counted vmcnt never drains fresh HBM loads.
#define KT_PHASE(KT, C, N, LAST)                                               \
  {                                                                            \
    LOADEB_ALL(KT)                                                             \
    LOADMW(KT)                                                                 \
    if (!(LAST)) LOADKT(N, (KT) + 1)                                           \
    MI_PHASE(0, C, e0a, e0b)                                                   \
    MI_PHASE(1, C, e1a, e1b)                                                   \
    MI_PHASE(2, C, e2a, e2b)                                                   \
    MI_PHASE(3, C, e3a, e3b)                                                   \
  }

  float lsum[4] = {0.f, 0.f, 0.f, 0.f};
  f32x4 o_acc[4][2];
#pragma unroll
  for (int mi = 0; mi < 4; ++mi)
#pragma unroll
    for (int no = 0; no < 2; ++no) o_acc[mi][no] = (f32x4){0.f, 0.f, 0.f, 0.f};

  LOADKT(A, 0)

  KT_PHASE(0, A, B, 0)
  KT_PHASE(1, B, A, 0)
  KT_PHASE(2, A, B, 0)
  KT_PHASE(3, B, A, 1)

#undef LOADKT
#undef LOADEB_ALL
#undef LOADMW
#undef NJ_STEP
#undef MI_PHASE
#undef KT_PHASE

  // epilogue: O^T tile (row dh = no*16+quad*4+r, col q = wm+mi*16+lr).
#pragma unroll
  for (int mi = 0; mi < 4; ++mi) {
    float ls = lsum[mi];
    ls += __shfl_xor(ls, 16);
    ls += __shfl_xor(ls, 32);
    float inv = (ls > 0.f) ? 1.f / ls : 0.f;
    int q = wm + mi * 16 + lr;
#pragma unroll
    for (int no = 0; no < 2; ++no) {
      f32x4 o = o_acc[mi][no];
      ushort4 w;
      w.x = __bfloat16_as_ushort(__float2bfloat16(o[0] * inv));
      w.y = __bfloat16_as_ushort(__float2bfloat16(o[1] * inv));
      w.z = __bfloat16_as_ushort(__float2bfloat16(o[2] * inv));
      w.w = __bfloat16_as_ushort(__float2bfloat16(o[3] * inv));
      *(ushort4*)(ao + (size_t)n * (LL * DD) + (size_t)q * DD +
                  h * DHH + no * 16 + quad * 4) = w;
    }
  }
}

extern "C" void kernel_launch(void* const* d_in, const int* in_sizes, int n_in,
                              void* d_out, int out_size, void* d_ws, size_t ws_size,
                              hipStream_t stream) {
  const float* msa   = (const float*)d_in[0];
  const float* pair  = (const float*)d_in[1];
  const unsigned char* mask = (const unsigned char*)d_in[2];
  const float* w_qkv = (const float*)d_in[3];
  const float* w_pb  = (const float*)d_in[4];
  const float* b_pb  = (const float*)d_in[5];
  const float* w_out = (const float*)d_in[6];
  const float* b_out = (const float*)d_in[7];
  float* out = (float*)d_out;

  char* ws = (char*)d_ws;
  __hip_bfloat16* qb      = (__hip_bfloat16*)(ws);                 // 16 MB
  __hip_bfloat16* kb      = (__hip_bfloat16*)(ws + 16777216);      // 16 MB
  __hip_bfloat16* vb      = (__hip_bfloat16*)(ws + 33554432);      // 16 MB [n][h][dh][k']
  __hip_bfloat16* msa_c   = (__hip_bfloat16*)(ws + 50331648);      // 16 MB
  __hip_bfloat16* ao      = (__hip_bfloat16*)(ws + 50331648);      // alias (msa dead after qkv)
  __hip_bfloat16* expb    = (__hip_bfloat16*)(ws + 67108864);      // 1 MB [h][q][k'] bf16
  __hip_bfloat16* wqkv_t  = (__hip_bfloat16*)(ws + 71303168);      // 384 KB
  __hip_bfloat16* wout_t  = (__hip_bfloat16*)(ws + 71696384);      // 128 KB
  float*          msk     = (float*)(ws + 71827456);               // 128 KB [n][k']

  mask_expand<<<32, 256, 0, stream>>>(mask, msk);
  cvt_bf16<<<1024, 256, 0, stream>>>(msa, msa_c, NN * LL * DD);
  transpose_cvt<<<dim3(24, 8), 256, 0, stream>>>(w_qkv, wqkv_t, 256, 768);
  transpose_cvt<<<dim3(8, 8), 256, 0, stream>>>(w_out, wout_t, 256, 256);

  qkv_gemm_mfma<<<dim3(256, 6), 256, 0, stream>>>(msa_c, wqkv_t, qb, kb, vb);
  pair_bias_kernel<<<2048, 256, 0, stream>>>(pair, w_pb, b_pb, expb);
  attn_mfma<<<1024, 256, 0, stream>>>(qb, kb, vb, expb, msk, ao);
  out_gemm_mfma<<<dim3(256, 2), 256, 0, stream>>>(ao, wout_t, b_out, out);
}

// Round 6
// 224.528 us; speedup vs baseline: 1.3440x; 1.0763x over previous
//
#include <hip/hip_runtime.h>
#include <hip/hip_bf16.h>

// Problem constants: B=1, N=128, L=256, D=256, P=128, H=8, DH=32
// Established: fp32 inputs, fp32 output; bf16-rounded ref, threshold 0.0289.
#define NN 128
#define LL 256
#define DD 256
#define PP 128
#define HH 8
#define DHH 32

typedef __bf16 bf16x8 __attribute__((ext_vector_type(8)));
typedef short s16x4 __attribute__((ext_vector_type(4)));
typedef short s16x8 __attribute__((ext_vector_type(8)));
typedef float f32x4 __attribute__((ext_vector_type(4)));
typedef unsigned int u32x2 __attribute__((ext_vector_type(2)));

// k' permutation: within each 64-block, swap bits[5:4] (nj) with bits[3:2]
// (quad) so that a lane's MFMA-fragment elements become CONTIGUOUS 16
// values. Self-inverse. Applied at the producers for expb, vb, msk.
__device__ __forceinline__ int permk(int k) {
  return (k & 0xC3) | ((k & 0x30) >> 2) | ((k & 0x0C) << 2);
}

// async global->LDS, 16B per lane (dest = wave-uniform base + lane*16)
__device__ __forceinline__ void gload_lds16(const void* g, void* l) {
  __builtin_amdgcn_global_load_lds(
      (const __attribute__((address_space(1))) void*)g,
      (__attribute__((address_space(3))) void*)l, 16, 0, 0);
}

// ---------------------------------------------------------------------------
// fp32 -> bf16 bulk convert
// ---------------------------------------------------------------------------
__global__ __launch_bounds__(256) void cvt_bf16(
    const float* __restrict__ src, __hip_bfloat16* __restrict__ dst, int n) {
  for (int i = (blockIdx.x * 256 + threadIdx.x) * 4; i < n; i += gridDim.x * 1024) {
    float4 v = *(const float4*)(src + i);
    ushort4 o;
    o.x = __bfloat16_as_ushort(__float2bfloat16(v.x));
    o.y = __bfloat16_as_ushort(__float2bfloat16(v.y));
    o.z = __bfloat16_as_ushort(__float2bfloat16(v.z));
    o.w = __bfloat16_as_ushort(__float2bfloat16(v.w));
    *(ushort4*)(dst + i) = o;
  }
}

// ---------------------------------------------------------------------------
// transpose + convert: src [K][N] fp32 -> dst [N][K] bf16
// ---------------------------------------------------------------------------
__global__ __launch_bounds__(256) void transpose_cvt(
    const float* __restrict__ src, __hip_bfloat16* __restrict__ dst,
    int K, int N) {
  __shared__ float t[32][33];
  int n0 = blockIdx.x * 32, k0 = blockIdx.y * 32;
  int tx = threadIdx.x & 31, ty = threadIdx.x >> 5;
  for (int i = 0; i < 4; ++i) {
    int ky = ty + i * 8;
    t[ky][tx] = src[(size_t)(k0 + ky) * N + n0 + tx];
  }
  __syncthreads();
  for (int i = 0; i < 4; ++i) {
    int ny = ty + i * 8;
    dst[(size_t)(n0 + ny) * K + k0 + tx] = __float2bfloat16(t[tx][ny]);
  }
}

// ---------------------------------------------------------------------------
// mask normalization -> float 1.0/0.0 at k'-PERMUTED index
// ---------------------------------------------------------------------------
#define MODE_I32 0
#define MODE_I8 1
#define MODE_BF16 2
#define MODE_F32 3

__global__ __launch_bounds__(256) void mask_expand(
    const unsigned char* __restrict__ mraw, float* __restrict__ mout) {
  __shared__ int s_or1, s_or2, s_or3, s_max, s_mode;
  int tid = threadIdx.x;
  if (tid == 0) { s_or1 = 0; s_or2 = 0; s_or3 = 0; s_max = 0; }
  __syncthreads();
  int or1 = 0, or2 = 0, or3 = 0, mx = 0;
  for (int j = tid; j < 4096; j += 256) {
    int b = mraw[j];
    mx = mx > b ? mx : b;
    int r = j & 3;
    if (r == 1) or1 |= b;
    else if (r == 2) or2 |= b;
    else if (r == 3) or3 |= b;
  }
  atomicOr(&s_or1, or1); atomicOr(&s_or2, or2); atomicOr(&s_or3, or3);
  atomicMax(&s_max, mx);
  __syncthreads();
  if (tid == 0) {
    int mode;
    if (s_max <= 1) mode = ((s_or1 | s_or2 | s_or3) == 0) ? MODE_I32 : MODE_I8;
    else            mode = (s_or1 != 0) ? MODE_BF16 : MODE_F32;
    s_mode = mode;
  }
  __syncthreads();
  int mode = s_mode;
  int i0 = blockIdx.x * 1024;
  for (int i = i0 + tid; i < i0 + 1024; i += 256) {
    int v;
    if (mode == MODE_I32)       v = ((const int*)mraw)[i] != 0;
    else if (mode == MODE_I8)   v = mraw[i] != 0;
    else if (mode == MODE_BF16) v = ((const unsigned short*)mraw)[i] != 0;
    else                        v = ((const unsigned int*)mraw)[i] != 0;
    mout[(i & ~255) | permk(i & 255)] = v ? 1.f : 0.f;
  }
}

// ---------------------------------------------------------------------------
// MFMA GEMM pipeline (A [M][256] bf16, Bt [N][256] bf16 = B^T).
// 128x128 tile, BK=32, 4 waves of 64x64, SWAPPED mfma (C^T fragments: lane
// holds 4 consecutive gcol at one grow -> wide coalesced stores).
// 2-phase LDS double-buffer: STAGE(t+1) issued BEFORE ds_read/MFMA of t;
// the single per-phase barrier drains loads that had a full phase to land
// (round-4 counters: serial stage->barrier->compute was pure latency,
// MfmaUtil 9% / VALU 11% / HBM 22%).
// XOR-swizzle (4-way from 8-way bank conflict) via pre-swizzled global
// source (global_load_lds dest must stay linear): slot' = slot ^ (row&3).
// NOTE: Aptr/Btptr are REAL LOCALS bound inside GEMM_PIPELINE (macro-scope
// fix for round-5 compile failure: GSTAGE expands on rescan, after
// GEMM_PIPELINE's parameter substitution).
// ---------------------------------------------------------------------------
#define GSTAGE(AD, BD, KS)                                                    \
  {                                                                           \
    const int k0_ = (KS) * 32;                                                \
    gload_lds16(Aptr + ((size_t)(bm * 128 + srow)) * 256 + k0_ + scc * 8,     \
                AD + (size_t)(wv * 64) * 8);                                  \
    gload_lds16(Btptr + ((size_t)(bn * 128 + srow)) * 256 + k0_ + scc * 8,    \
                BD + (size_t)(wv * 64) * 8);                                  \
    gload_lds16(Aptr + ((size_t)(bm * 128 + 64 + srow)) * 256 + k0_ + scc * 8,\
                AD + (size_t)(wv * 64 + 256) * 8);                            \
    gload_lds16(Btptr + ((size_t)(bn * 128 + 64 + srow)) * 256 + k0_ + scc * 8,\
                BD + (size_t)(wv * 64 + 256) * 8);                            \
  }

#define GPHASE(CA, CB, NA, NB, NKS, DOSTAGE)                                  \
  {                                                                           \
    if (DOSTAGE) GSTAGE(NA, NB, NKS)                                          \
    bf16x8 af[4], bfr[4];                                                     \
    _Pragma("unroll") for (int mi = 0; mi < 4; ++mi) {                        \
      int r_ = wm + mi * 16 + lr;                                             \
      af[mi] = *(const bf16x8*)&CA[r_ * 32 + (quad ^ (r_ & 3)) * 8];          \
    }                                                                         \
    _Pragma("unroll") for (int ni = 0; ni < 4; ++ni) {                        \
      int r_ = wn + ni * 16 + lr;                                             \
      bfr[ni] = *(const bf16x8*)&CB[r_ * 32 + (quad ^ (r_ & 3)) * 8];         \
    }                                                                         \
    _Pragma("unroll") for (int mi = 0; mi < 4; ++mi)                          \
      _Pragma("unroll") for (int ni = 0; ni < 4; ++ni)                        \
        acc[mi][ni] = __builtin_amdgcn_mfma_f32_16x16x32_bf16(                \
            bfr[ni], af[mi], acc[mi][ni], 0, 0, 0);                           \
  }                                                                           \
  __syncthreads();

#define GEMM_PIPELINE(APTR_, BTPTR_)                                          \
  const __hip_bfloat16* __restrict__ Aptr = (APTR_);                          \
  const __hip_bfloat16* __restrict__ Btptr = (BTPTR_);                        \
  __shared__ __align__(16) __hip_bfloat16 As0[128 * 32], As1[128 * 32];       \
  __shared__ __align__(16) __hip_bfloat16 Bs0[128 * 32], Bs1[128 * 32];       \
  int tid = threadIdx.x;                                                      \
  int lane = tid & 63, wv = tid >> 6;                                         \
  int wm = (wv >> 1) * 64, wn = (wv & 1) * 64;                                \
  int lr = lane & 15, quad = lane >> 4;                                       \
  int bm = blockIdx.x, bn = blockIdx.y;                                       \
  int srow = tid >> 2, sslot = tid & 3;                                       \
  int scc = sslot ^ (srow & 3);                                               \
  f32x4 acc[4][4];                                                            \
  for (int i = 0; i < 4; ++i)                                                 \
    for (int j = 0; j < 4; ++j) acc[i][j] = (f32x4){0.f, 0.f, 0.f, 0.f};      \
  GSTAGE(As0, Bs0, 0)                                                         \
  __syncthreads();                                                            \
  GPHASE(As0, Bs0, As1, Bs1, 1, 1)                                            \
  GPHASE(As1, Bs1, As0, Bs0, 2, 1)                                            \
  GPHASE(As0, Bs0, As1, Bs1, 3, 1)                                            \
  GPHASE(As1, Bs1, As0, Bs0, 4, 1)                                            \
  GPHASE(As0, Bs0, As1, Bs1, 5, 1)                                            \
  GPHASE(As1, Bs1, As0, Bs0, 6, 1)                                            \
  GPHASE(As0, Bs0, As1, Bs1, 7, 1)                                            \
  GPHASE(As1, Bs1, As0, Bs0, 8, 0)

// QKV: q,k -> [n][h][l][dh]; v -> [n][h][dh][l'] (transposed + k'-permuted).
// Swapped acc: lane holds gcol = bn*128+wn+ni*16+quad*4+r (r contiguous dh),
// grow = bm*128+wm+mi*16+lr. t = bn>>1 uniform per block.
__global__ __launch_bounds__(256) void qkv_gemm_mfma(
    const __hip_bfloat16* __restrict__ A,
    const __hip_bfloat16* __restrict__ Bt,
    __hip_bfloat16* __restrict__ qb,
    __hip_bfloat16* __restrict__ kb,
    __hip_bfloat16* __restrict__ vb) {
  GEMM_PIPELINE(A, Bt)
  int t = bn >> 1;
#pragma unroll
  for (int mi = 0; mi < 4; ++mi) {
    int g = bm * 128 + wm + mi * 16 + lr;
    int n = g >> 8, l = g & 255;
    int lp = permk(l);
#pragma unroll
    for (int ni = 0; ni < 4; ++ni) {
      int rem = (bn * 128 + wn + ni * 16 + quad * 4) & 255;
      int h = rem >> 5, dh0 = rem & 31;
      if (t < 2) {
        ushort4 w;
        w.x = __bfloat16_as_ushort(__float2bfloat16(acc[mi][ni][0]));
        w.y = __bfloat16_as_ushort(__float2bfloat16(acc[mi][ni][1]));
        w.z = __bfloat16_as_ushort(__float2bfloat16(acc[mi][ni][2]));
        w.w = __bfloat16_as_ushort(__float2bfloat16(acc[mi][ni][3]));
        __hip_bfloat16* dst = (t == 0 ? qb : kb);
        *(ushort4*)(dst + ((size_t)((n * HH + h) * LL + l)) * DHH + dh0) = w;
      } else {
#pragma unroll
        for (int r = 0; r < 4; ++r)
          vb[((size_t)((n * HH + h) * DHH + dh0 + r)) * LL + lp] =
              __float2bfloat16(acc[mi][ni][r]);
      }
    }
  }
}

__global__ __launch_bounds__(256) void out_gemm_mfma(
    const __hip_bfloat16* __restrict__ A,
    const __hip_bfloat16* __restrict__ Bt,
    const float* __restrict__ bout,
    float* __restrict__ C) {
  GEMM_PIPELINE(A, Bt)
#pragma unroll
  for (int mi = 0; mi < 4; ++mi) {
    int g = bm * 128 + wm + mi * 16 + lr;
#pragma unroll
    for (int ni = 0; ni < 4; ++ni) {
      int gcol0 = bn * 128 + wn + ni * 16 + quad * 4;
      float4 bo = *(const float4*)(bout + gcol0);
      float4 v;
      v.x = acc[mi][ni][0] + bo.x;
      v.y = acc[mi][ni][1] + bo.y;
      v.z = acc[mi][ni][2] + bo.z;
      v.w = acc[mi][ni][3] + bo.w;
      *(float4*)(C + (size_t)g * 256 + gcol0) = v;
    }
  }
}

// ---------------------------------------------------------------------------
// pair bias -> expb[h][q][k'] = exp(pair@w_pb + b_pb - 12) bf16, k'-permuted.
// ---------------------------------------------------------------------------
__global__ __launch_bounds__(256) void pair_bias_kernel(
    const float* __restrict__ pair,
    const float* __restrict__ w_pb,
    const float* __restrict__ b_pb,
    __hip_bfloat16* __restrict__ expb) {
  __shared__ float wp[128][9];
  __shared__ float rows[32][129];
  int tid = threadIdx.x;
  for (int i = 0; i < 4; ++i) {
    int e = tid + i * 256;
    wp[e >> 3][e & 7] = w_pb[e];
  }
  int row0 = blockIdx.x * 32;
  const float* src = pair + (size_t)row0 * PP;
  for (int i = 0; i < 16; ++i) {
    int e = tid + i * 256;
    int r = e >> 7, c = e & 127;
    rows[r][c] = src[r * 128 + c];
  }
  __syncthreads();
  int h = tid >> 5, rl = tid & 31;
  float acc = b_pb[h] - 12.0f;
  for (int p = 0; p < 128; ++p)
    acc += rows[rl][p] * wp[p][h];
  int row = row0 + rl;
  int i = row >> 8, j = row & 255;
  expb[((size_t)(h * LL + i)) * LL + permk(j)] = __float2bfloat16(__expf(acc));
}

// ---------------------------------------------------------------------------
// Flash-style MFMA attention: zero LDS, swapped QK^T, fixed-shift softmax,
// pre-exponentiated bf16 bias, k'-permuted operand layouts (round-4 version;
// broke the 59us latency plateau via contiguous fragments + per-kt grouped
// issue order [eb, mask, K/V(kt+1)] so consumption is strictly issue-ordered
// under the in-order vmcnt counter).
// ---------------------------------------------------------------------------
__global__ __launch_bounds__(256, 2) void attn_mfma(
    const __hip_bfloat16* __restrict__ qb,
    const __hip_bfloat16* __restrict__ kb,
    const __hip_bfloat16* __restrict__ vbt,   // [n][h][dh][k'] bf16
    const __hip_bfloat16* __restrict__ expb,  // [h][q][k'] = exp(bias-12) bf16
    const float* __restrict__ maskf,          // [n][k'] 1.0/0.0
    __hip_bfloat16* __restrict__ ao) {
  int bx = blockIdx.x;
  int h = bx >> 7, n = bx & 127;
  int nh = n * HH + h;
  int tid = threadIdx.x, lane = tid & 63, wv = tid >> 6;
  int lr = lane & 15, quad = lane >> 4;
  int wm = wv * 64;
  size_t base = (size_t)nh * (LL * DHH);

  const __hip_bfloat16* qp = qb + base;
  const __hip_bfloat16* kp = kb + base;
  const __hip_bfloat16* vp = vbt + base;
  const __hip_bfloat16* ep = expb + (size_t)h * LL * LL;
  const float* mrow = maskf + n * LL;

  const float cs = 0.17677669529663687f * 1.4426950408889634f;  // scale*log2e

  // Q fragments (row q = wm+mi*16+lr, dh = quad*8..+7); B-operand of QK^T.
  bf16x8 aq[4];
#pragma unroll
  for (int mi = 0; mi < 4; ++mi)
    aq[mi] = *(const bf16x8*)(qp + (size_t)(wm + mi * 16 + lr) * DHH + quad * 8);

  // K double-buffered (A/B tokens); V likewise (contig 16B halves a/b per no).
  bf16x8 bkA[4], bkB[4];
  s16x8 avA0a, avA0b, avA1a, avA1b;
  s16x8 avB0a, avB0b, avB1a, avB1b;
  // eb: all 4 mi of the CURRENT kt, single-buffered (2x16B per mi).
  uint4 e0a, e0b, e1a, e1b, e2a, e2b, e3a, e3b;
  // mask multipliers for current kt (k'-contiguous).
  f32x4 mw0, mw1, mw2, mw3;

#define LOADKT(S, KT)                                                          \
  {                                                                            \
    const int j0_ = (KT) * 64;                                                 \
    _Pragma("unroll") for (int nj = 0; nj < 4; ++nj)                           \
        bk##S[nj] =                                                            \
        *(const bf16x8*)(kp + (size_t)(j0_ + nj * 16 + lr) * DHH + quad * 8);  \
    av##S##0a = *(const s16x8*)(vp + (size_t)lr * LL + j0_ + quad * 16);       \
    av##S##0b = *(const s16x8*)(vp + (size_t)lr * LL + j0_ + quad * 16 + 8);   \
    av##S##1a = *(const s16x8*)(vp + (size_t)(16 + lr) * LL + j0_ + quad * 16);\
    av##S##1b =                                                                \
        *(const s16x8*)(vp + (size_t)(16 + lr) * LL + j0_ + quad * 16 + 8);    \
  }

#define LOADEB_ALL(KT)                                                         \
  {                                                                            \
    const int j0_ = (KT) * 64;                                                 \
    e0a = *(const uint4*)(ep + (size_t)(wm + 0 + lr) * LL + j0_ + quad * 16);  \
    e0b = *(const uint4*)(ep + (size_t)(wm + 0 + lr) * LL + j0_ + quad * 16 + 8);\
    e1a = *(const uint4*)(ep + (size_t)(wm + 16 + lr) * LL + j0_ + quad * 16); \
    e1b = *(const uint4*)(ep + (size_t)(wm + 16 + lr) * LL + j0_ + quad * 16 + 8);\
    e2a = *(const uint4*)(ep + (size_t)(wm + 32 + lr) * LL + j0_ + quad * 16); \
    e2b = *(const uint4*)(ep + (size_t)(wm + 32 + lr) * LL + j0_ + quad * 16 + 8);\
    e3a = *(const uint4*)(ep + (size_t)(wm + 48 + lr) * LL + j0_ + quad * 16); \
    e3b = *(const uint4*)(ep + (size_t)(wm + 48 + lr) * LL + j0_ + quad * 16 + 8);\
  }

#define LOADMW(KT)                                                             \
  {                                                                            \
    const int j0_ = (KT) * 64;                                                 \
    mw0 = *(const f32x4*)(mrow + j0_ + quad * 16 + 0);                         \
    mw1 = *(const f32x4*)(mrow + j0_ + quad * 16 + 4);                         \
    mw2 = *(const f32x4*)(mrow + j0_ + quad * 16 + 8);                         \
    mw3 = *(const f32x4*)(mrow + j0_ + quad * 16 + 12);                        \
  }

// One nj step of one (kt,mi) phase. EX/EY = the two eb dwords for this nj,
// AV0/AV1 = 16B V fragments (no=0,1), LO = element offset (0 or 4).
#define NJ_STEP(C, MI, NJ, EX, EY, AV0, AV1, LO)                               \
  {                                                                            \
    f32x4 s_ = __builtin_amdgcn_mfma_f32_16x16x32_bf16(                        \
        bk##C[NJ], aq[MI], (f32x4){0.f, 0.f, 0.f, 0.f}, 0, 0, 0);              \
    float em0_ = __uint_as_float((EX) << 16) * mw##NJ[0];                      \
    float em1_ = __uint_as_float((EX) & 0xffff0000u) * mw##NJ[1];              \
    float em2_ = __uint_as_float((EY) << 16) * mw##NJ[2];                      \
    float em3_ = __uint_as_float((EY) & 0xffff0000u) * mw##NJ[3];              \
    float p0_ = exp2f(s_[0] * cs) * em0_;                                      \
    float p1_ = exp2f(s_[1] * cs) * em1_;                                      \
    float p2_ = exp2f(s_[2] * cs) * em2_;                                      \
    float p3_ = exp2f(s_[3] * cs) * em3_;                                      \
    lsum[MI] += (p0_ + p1_) + (p2_ + p3_);                                     \
    unsigned lo_ =                                                             \
        ((unsigned)__bfloat16_as_ushort(__float2bfloat16(p1_)) << 16) |        \
        (unsigned)__bfloat16_as_ushort(__float2bfloat16(p0_));                 \
    unsigned hi_ =                                                             \
        ((unsigned)__bfloat16_as_ushort(__float2bfloat16(p3_)) << 16) |        \
        (unsigned)__bfloat16_as_ushort(__float2bfloat16(p2_));                 \
    u32x2 pu_ = {lo_, hi_};                                                    \
    s16x4 pb_ = __builtin_bit_cast(s16x4, pu_);                                \
    s16x4 a0_ = __builtin_shufflevector(AV0, AV0, LO, LO + 1, LO + 2, LO + 3); \
    s16x4 a1_ = __builtin_shufflevector(AV1, AV1, LO, LO + 1, LO + 2, LO + 3); \
    o_acc[MI][0] = __builtin_amdgcn_mfma_f32_16x16x16bf16_1k(                  \
        a0_, pb_, o_acc[MI][0], 0, 0, 0);                                      \
    o_acc[MI][1] = __builtin_amdgcn_mfma_f32_16x16x16bf16_1k(                  \
        a1_, pb_, o_acc[MI][1], 0, 0, 0);                                      \
  }

#define MI_PHASE(MI, C, EA, EB_)                                               \
  {                                                                            \
    NJ_STEP(C, MI, 0, EA.x, EA.y, av##C##0a, av##C##1a, 0)                     \
    NJ_STEP(C, MI, 1, EA.z, EA.w, av##C##0a, av##C##1a, 4)                     \
    NJ_STEP(C, MI, 2, EB_.x, EB_.y, av##C##0b, av##C##1b, 0)                   \
    NJ_STEP(C, MI, 3, EB_.z, EB_.w, av##C##0b, av##C##1b, 4)                   \
  }

// Issue order per kt: eb (needed in ~1 phase, L2) first, then mask, then the
// NEXT kt's K/V (HBM, consumed a full kt later). Consumption is strictly in
// issue order -> compiler's counted vmcnt never drains fresh HBM loads.
#define KT_PHASE(KT, C, N, LAST)                                               \
  {                                                                            \
    LOADEB_ALL(KT)                                                             \
    LOADMW(KT)                                                                 \
    if (!(LAST)) LOADKT(N, (KT) + 1)                                           \
    MI_PHASE(0, C, e0a, e0b)                                                   \
    MI_PHASE(1, C, e1a, e1b)                                                   \
    MI_PHASE(2, C, e2a, e2b)                                                   \
    MI_PHASE(3, C, e3a, e3b)                                                   \
  }

  float lsum[4] = {0.f, 0.f, 0.f, 0.f};
  f32x4 o_acc[4][2];
#pragma unroll
  for (int mi = 0; mi < 4; ++mi)
#pragma unroll
    for (int no = 0; no < 2; ++no) o_acc[mi][no] = (f32x4){0.f, 0.f, 0.f, 0.f};

  LOADKT(A, 0)

  KT_PHASE(0, A, B, 0)
  KT_PHASE(1, B, A, 0)
  KT_PHASE(2, A, B, 0)
  KT_PHASE(3, B, A, 1)

#undef LOADKT
#undef LOADEB_ALL
#undef LOADMW
#undef NJ_STEP
#undef MI_PHASE
#undef KT_PHASE

  // epilogue: O^T tile (row dh = no*16+quad*4+r, col q = wm+mi*16+lr).
#pragma unroll
  for (int mi = 0; mi < 4; ++mi) {
    float ls = lsum[mi];
    ls += __shfl_xor(ls, 16);
    ls += __shfl_xor(ls, 32);
    float inv = (ls > 0.f) ? 1.f / ls : 0.f;
    int q = wm + mi * 16 + lr;
#pragma unroll
    for (int no = 0; no < 2; ++no) {
      f32x4 o = o_acc[mi][no];
      ushort4 w;
      w.x = __bfloat16_as_ushort(__float2bfloat16(o[0] * inv));
      w.y = __bfloat16_as_ushort(__float2bfloat16(o[1] * inv));
      w.z = __bfloat16_as_ushort(__float2bfloat16(o[2] * inv));
      w.w = __bfloat16_as_ushort(__float2bfloat16(o[3] * inv));
      *(ushort4*)(ao + (size_t)n * (LL * DD) + (size_t)q * DD +
                  h * DHH + no * 16 + quad * 4) = w;
    }
  }
}

extern "C" void kernel_launch(void* const* d_in, const int* in_sizes, int n_in,
                              void* d_out, int out_size, void* d_ws, size_t ws_size,
                              hipStream_t stream) {
  const float* msa   = (const float*)d_in[0];
  const float* pair  = (const float*)d_in[1];
  const unsigned char* mask = (const unsigned char*)d_in[2];
  const float* w_qkv = (const float*)d_in[3];
  const float* w_pb  = (const float*)d_in[4];
  const float* b_pb  = (const float*)d_in[5];
  const float* w_out = (const float*)d_in[6];
  const float* b_out = (const float*)d_in[7];
  float* out = (float*)d_out;

  char* ws = (char*)d_ws;
  __hip_bfloat16* qb      = (__hip_bfloat16*)(ws);                 // 16 MB
  __hip_bfloat16* kb      = (__hip_bfloat16*)(ws + 16777216);      // 16 MB
  __hip_bfloat16* vb      = (__hip_bfloat16*)(ws + 33554432);      // 16 MB [n][h][dh][k']
  __hip_bfloat16* msa_c   = (__hip_bfloat16*)(ws + 50331648);      // 16 MB
  __hip_bfloat16* ao      = (__hip_bfloat16*)(ws + 50331648);      // alias (msa dead after qkv)
  __hip_bfloat16* expb    = (__hip_bfloat16*)(ws + 67108864);      // 1 MB [h][q][k'] bf16
  __hip_bfloat16* wqkv_t  = (__hip_bfloat16*)(ws + 71303168);      // 384 KB
  __hip_bfloat16* wout_t  = (__hip_bfloat16*)(ws + 71696384);      // 128 KB
  float*          msk     = (float*)(ws + 71827456);               // 128 KB [n][k']

  mask_expand<<<32, 256, 0, stream>>>(mask, msk);
  cvt_bf16<<<1024, 256, 0, stream>>>(msa, msa_c, NN * LL * DD);
  transpose_cvt<<<dim3(24, 8), 256, 0, stream>>>(w_qkv, wqkv_t, 256, 768);
  transpose_cvt<<<dim3(8, 8), 256, 0, stream>>>(w_out, wout_t, 256, 256);

  qkv_gemm_mfma<<<dim3(256, 6), 256, 0, stream>>>(msa_c, wqkv_t, qb, kb, vb);
  pair_bias_kernel<<<2048, 256, 0, stream>>>(pair, w_pb, b_pb, expb);
  attn_mfma<<<1024, 256, 0, stream>>>(qb, kb, vb, expb, msk, ao);
  out_gemm_mfma<<<dim3(256, 2), 256, 0, stream>>>(ao, wout_t, b_out, out);
}